// Round 17
// baseline (1160.220 us; speedup 1.0000x reference)
//
#include <hip/hip_runtime.h>
#include <hip/hip_bf16.h>
#include <stdint.h>

#define TOKENS 8192
#define DIN    4096
#define DOUT   16384

#define BM 256
#define BN 256
#define BKT 64                 // K per tile
#define NT (DIN / BKT)         // 64 K-tiles
#define NJ (NT / 2)            // 32 iterations, 2 tiles each

typedef short s16x8 __attribute__((ext_vector_type(8)));
typedef float f32x16 __attribute__((ext_vector_type(16)));

#define AS1 __attribute__((address_space(1)))
#define AS3 __attribute__((address_space(3)))
#define VMCNT(n)  asm volatile("s_waitcnt vmcnt(" #n ")" ::: "memory")
#define BAR()     __builtin_amdgcn_s_barrier()

__device__ __forceinline__ unsigned short f2bf(float f) {
  unsigned int u = __float_as_uint(f);
  u += 0x7fffu + ((u >> 16) & 1u);   // round-to-nearest-even
  return (unsigned short)(u >> 16);
}

// -------- Kernel 1: LayerNorm fp32 -> bf16
__global__ __launch_bounds__(256) void ln_kernel(const float* __restrict__ x,
                                                 unsigned short* __restrict__ xn) {
  const int row = blockIdx.x;
  const float4* xr = reinterpret_cast<const float4*>(x + (size_t)row * DIN);
  float4 v[4];
  float sum = 0.f, ssq = 0.f;
#pragma unroll
  for (int i = 0; i < 4; ++i) {
    v[i] = xr[threadIdx.x + i * 256];
    sum += v[i].x + v[i].y + v[i].z + v[i].w;
    ssq += v[i].x * v[i].x + v[i].y * v[i].y + v[i].z * v[i].z + v[i].w * v[i].w;
  }
#pragma unroll
  for (int off = 32; off > 0; off >>= 1) {
    sum += __shfl_xor(sum, off, 64);
    ssq += __shfl_xor(ssq, off, 64);
  }
  __shared__ float red[8];
  const int wid = threadIdx.x >> 6;
  if ((threadIdx.x & 63) == 0) { red[wid] = sum; red[wid + 4] = ssq; }
  __syncthreads();
  sum = red[0] + red[1] + red[2] + red[3];
  ssq = red[4] + red[5] + red[6] + red[7];
  const float mean = sum * (1.f / DIN);
  const float var  = ssq * (1.f / DIN) - mean * mean;
  const float rs   = rsqrtf(var + 1e-5f);
  ushort4* xo = reinterpret_cast<ushort4*>(xn + (size_t)row * DIN);
#pragma unroll
  for (int i = 0; i < 4; ++i) {
    ushort4 o;
    o.x = f2bf((v[i].x - mean) * rs);
    o.y = f2bf((v[i].y - mean) * rs);
    o.z = f2bf((v[i].z - mean) * rs);
    o.w = f2bf((v[i].w - mean) * rs);
    xo[threadIdx.x + i * 256] = o;
  }
}

// -------- Kernel 2: W fp32 -> bf16
__global__ __launch_bounds__(256) void cvt_kernel(const float* __restrict__ W,
                                                  unsigned short* __restrict__ Wb) {
  const size_t i = (size_t)blockIdx.x * 256 + threadIdx.x;
  float4 v = reinterpret_cast<const float4*>(W)[i];
  ushort4 o;
  o.x = f2bf(v.x); o.y = f2bf(v.y); o.z = f2bf(v.z); o.w = f2bf(v.w);
  reinterpret_cast<ushort4*>(Wb)[i] = o;
}

// -------- Kernel 3: 256x256, 32x32x16 MFMA, 4-phase, DECOUPLED v2.
// R17 vs R16: A1 re-stage moved ph3 -> ph4. R16's bug: ph3 staged A-buf1
// while ph3 also READ A-buf1 (old tile) — a lagging wave blocked at ph3's
// vmcnt reads AFTER a fast wave's stage-writes land (unbounded intra-phase
// skew when a blocking vmcnt precedes the read). Rule now enforced
// everywhere: a phase never stages a buffer it (or a concurrent phase)
// reads; every stage is >=1 barrier after the old region's last read:
//   stages: ph1 B0(t2) | ph2 A0(t2) | ph3 B1(t3) | ph4 A1(t3)   (4 each)
//   reads : ph1 A0(t0) full [aX in-phase, aY] | ph2 A1.mp0->aX, B1->bY
//           | ph3 A1.mp1->aY | ph4 B0(t2)->bX
//   vmcnt : ph1 0 (confirms B1,A1(t1) staged prev ph3/ph4)
//           ph3 4 (confirms B0(t2); leaves A0(t2))
//           ph4 4 (confirms A0(t2); leaves B1(t3))
// Confirm ledger (all earlier-phase-top vmcnt + end-barrier before read):
//   A0(t0): prev-ph4 vmcnt(4)+bar -> ph1.  A1/B1(t1): ph1 vmcnt(0)+bar ->
//   ph2/ph3.  B0(t2): ph3 vmcnt(4)+bar -> ph4.  A0(t2): ph4 vmcnt(4)+bar
//   -> next ph1.  Overwrite: B0 prev-ph4->ph1, A0 ph1->ph2, B1 ph2->ph3,
//   A1 ph3->ph4 — all >=1 barrier. Tail: all 4 stages + ph4 bX-read skip.
__global__ __launch_bounds__(512, 2) void gemm_sig(const unsigned short* __restrict__ A,
                                                   const unsigned short* __restrict__ B,
                                                   float* __restrict__ C) {
  __shared__ unsigned short Asl[2 * 256 * 64];  // 64 KB
  __shared__ unsigned short Bsl[2 * 256 * 64];  // 64 KB

  // XCD chunk (nwg=2048, cpx=256) then 2x2 super-tile grouping.
  const int bid = blockIdx.x;
  const int cpx = gridDim.x >> 3;              // 256
  const int swz = (bid & 7) * cpx + (bid >> 3);
  const int grp = swz >> 2;                    // 0..511 = 16 (bm) x 32 (bn)
  const int sub = swz & 3;
  const int bm = ((grp & 15) << 1) | (sub & 1);    // 0..31
  const int bn = ((grp >> 4) << 1) | (sub >> 1);   // 0..63

  const int tid  = threadIdx.x;
  const int wid  = tid >> 6;
  const int lane = tid & 63;
  const int wr = wid >> 2, wc = wid & 3;

  const unsigned short* gA = A + (size_t)bm * BM * DIN;
  const unsigned short* gB = B + (size_t)bn * BN * DIN;

  // Staging: 1 gload = 512 lanes x 16B = 8 KB = 64 rows (one quarter).
  // Lane l of wave wid writes LDS row wid*8+(l>>3), slot l&7 (linear dest);
  // fetches global slot (l&7)^(l>>3) (involution keyed on row&7).
  const int l8 = lane >> 3, l7 = lane & 7;
  const int csw = l7 ^ l8;
  const unsigned short* sA = gA + (size_t)(wid * 8 + l8) * DIN + csw * 8;
  const unsigned short* sB = gB + (size_t)(wid * 8 + l8) * DIN + csw * 8;
  const int dOfs = wid * 512;   // ushort units

#define STG_A(p, kt) do { _Pragma("unroll") for (int q = 0; q < 4; ++q) \
  __builtin_amdgcn_global_load_lds( \
    (const AS1 void*)(sA + (size_t)q * 64 * DIN + (size_t)(kt) * BKT), \
    (AS3 void*)(Asl + ((p) * 256 + q * 64) * 64 + dOfs), 16, 0, 0); } while (0)
#define STG_B(p, kt) do { _Pragma("unroll") for (int q = 0; q < 4; ++q) \
  __builtin_amdgcn_global_load_lds( \
    (const AS1 void*)(sB + (size_t)q * 64 * DIN + (size_t)(kt) * BKT), \
    (AS3 void*)(Bsl + ((p) * 256 + q * 64) * 64 + dOfs), 16, 0, 0); } while (0)

  // Read side (32x32 frags): row = base + (lane&31); logical k-slot for
  // kstep ks = 2*ks + (lane>>5); stored at slot ^ (row&7), row&7 = lane&7.
  const int l31 = lane & 31;
  const int l5  = lane >> 5;
  int aRow[4], bRow[2], kslt[4];
#pragma unroll
  for (int mb = 0; mb < 4; ++mb) aRow[mb] = (wr * 128 + mb * 32 + l31) * 64;
#pragma unroll
  for (int nb = 0; nb < 2; ++nb) bRow[nb] = (wc * 64 + nb * 32 + l31) * 64;
#pragma unroll
  for (int ks = 0; ks < 4; ++ks) kslt[ks] = ((2 * ks + l5) ^ l7) * 8;

  // aArr[ks] = row 2mp, aArr[4+ks] = row 2mp+1 ; bArr[nb*4+ks]
  s16x8 aX[8], aY[8], bX[8], bY[8];
  f32x16 acc[4][2] = {};

#define RD_AP(p, mp, dst) do { _Pragma("unroll") for (int ks = 0; ks < 4; ++ks) { \
    dst[ks]     = *reinterpret_cast<const s16x8*>(Asl + (p) * 16384 + aRow[2 * (mp)] + kslt[ks]); \
    dst[4 + ks] = *reinterpret_cast<const s16x8*>(Asl + (p) * 16384 + aRow[2 * (mp) + 1] + kslt[ks]); } } while (0)
#define RD_BPRE(p, dst) do { _Pragma("unroll") for (int ks = 0; ks < 4; ++ks) { \
    dst[ks]     = *reinterpret_cast<const s16x8*>(Bsl + (p) * 16384 + bRow[0] + kslt[ks]); \
    dst[4 + ks] = *reinterpret_cast<const s16x8*>(Bsl + (p) * 16384 + bRow[1] + kslt[ks]); } } while (0)
#define MMPH(mp, aArr, bArr) do { _Pragma("unroll") for (int ks = 0; ks < 4; ++ks) { \
    acc[2 * (mp)][0]     = __builtin_amdgcn_mfma_f32_32x32x16_bf16(aArr[ks],     bArr[ks],     acc[2 * (mp)][0], 0, 0, 0); \
    acc[2 * (mp)][1]     = __builtin_amdgcn_mfma_f32_32x32x16_bf16(aArr[ks],     bArr[4 + ks], acc[2 * (mp)][1], 0, 0, 0); \
    acc[2 * (mp) + 1][0] = __builtin_amdgcn_mfma_f32_32x32x16_bf16(aArr[4 + ks], bArr[ks],     acc[2 * (mp) + 1][0], 0, 0, 0); \
    acc[2 * (mp) + 1][1] = __builtin_amdgcn_mfma_f32_32x32x16_bf16(aArr[4 + ks], bArr[4 + ks], acc[2 * (mp) + 1][1], 0, 0, 0); } } while (0)

  // Prologue: A(0),B(0) then A(1),B(1). vmcnt(8) confirms tile0 (incl.
  // B-buf0 for the bX preload); publish; prefetch bX <- B(0).
  STG_A(0, 0); STG_B(0, 0);
  STG_A(1, 1); STG_B(1, 1);
  VMCNT(8); BAR();
  RD_BPRE(0, bX);

  for (int j = 0; j < NJ; ++j) {
    const int t2 = 2 * j + 2, t3 = 2 * j + 3;
    const bool last = (j == NJ - 1);
    // ph1: vmcnt(0) confirms A1,B1(t1) [staged prev ph3/ph4];
    //      reads A(t0) full (aX in-phase, aY next-phase); stage B0(t2);
    //      MFMA mp0(t0) x bX
    VMCNT(0);
    RD_AP(0, 0, aX); RD_AP(0, 1, aY);
    if (!last) STG_B(0, t2);
    MMPH(0, aX, bX); BAR();
    // ph2: reads A1.mp0(t1) -> aX, B1(t1) -> bY; stage A0(t2);
    //      MFMA mp1(t0) x bX [aY]
    RD_AP(1, 0, aX); RD_BPRE(1, bY);
    if (!last) STG_A(0, t2);
    MMPH(1, aY, bX); BAR();
    // ph3: vmcnt(4) confirms B0(t2) [staged ph1; leaves A0(t2)];
    //      reads A1.mp1(t1) -> aY; stage B1(t3);
    //      MFMA mp0(t1) x bY [aX]
    VMCNT(4);
    RD_AP(1, 1, aY);
    if (!last) STG_B(1, t3);
    MMPH(0, aX, bY); BAR();
    // ph4: vmcnt(4) confirms A0(t2) [leaves B1(t3)];
    //      reads B0(t2) -> bX (next iter); stage A1(t3);
    //      MFMA mp1(t1) x bY [aY]
    VMCNT(4);
    if (!last) { RD_BPRE(0, bX); STG_A(1, t3); }
    MMPH(1, aY, bY); BAR();
  }

#undef STG_A
#undef STG_B
#undef RD_AP
#undef RD_BPRE
#undef MMPH

  // Epilogue: 32x32 C/D layout: col = lane&31,
  // row = (reg&3) + 8*(reg>>2) + 4*(lane>>5).
  const int crow0 = bm * BM + wr * 128 + 4 * l5;
  const int ccol0 = bn * BN + wc * 64 + l31;
#pragma unroll
  for (int mb = 0; mb < 4; ++mb)
#pragma unroll
    for (int nb = 0; nb < 2; ++nb)
#pragma unroll
      for (int reg = 0; reg < 16; ++reg) {
        const int r = crow0 + mb * 32 + (reg & 3) + 8 * (reg >> 2);
        const int c = ccol0 + nb * 32;
        const float v = acc[mb][nb][reg];
        C[(size_t)r * DOUT + c] = 1.f / (1.f + __expf(-v));
      }
}

extern "C" void kernel_launch(void* const* d_in, const int* in_sizes, int n_in,
                              void* d_out, int out_size, void* d_ws, size_t ws_size,
                              hipStream_t stream) {
  const float* x = (const float*)d_in[0];
  const float* W = (const float*)d_in[1];
  float* out = (float*)d_out;

  unsigned short* xn = (unsigned short*)d_ws;                    // 64 MiB
  unsigned short* Wb = xn + (size_t)TOKENS * DIN;                // 128 MiB

  ln_kernel<<<TOKENS, 256, 0, stream>>>(x, xn);
  cvt_kernel<<<((size_t)DOUT * DIN) / 1024, 256, 0, stream>>>(W, Wb);
  gemm_sig<<<(TOKENS / BM) * (DOUT / BN), 512, 0, stream>>>(xn, Wb, out);
}

// Round 18
// 1124.204 us; speedup vs baseline: 1.0320x; 1.0320x over previous
//
#include <hip/hip_runtime.h>
#include <hip/hip_bf16.h>
#include <stdint.h>

#define TOKENS 8192
#define DIN    4096
#define DOUT   16384

#define BM 256
#define BN 256
#define BKT 64                 // K per tile
#define NT (DIN / BKT)         // 64 K-tiles
#define NJ (NT / 2)            // 32 iterations, 2 tiles each

typedef short s16x8 __attribute__((ext_vector_type(8)));
typedef float f32x16 __attribute__((ext_vector_type(16)));

#define AS1 __attribute__((address_space(1)))
#define AS3 __attribute__((address_space(3)))
#define VMCNT(n)  asm volatile("s_waitcnt vmcnt(" #n ")" ::: "memory")
#define BAR()     __builtin_amdgcn_s_barrier()
#define PRIO1()   __builtin_amdgcn_s_setprio(1)
#define PRIO0()   __builtin_amdgcn_s_setprio(0)

__device__ __forceinline__ unsigned short f2bf(float f) {
  unsigned int u = __float_as_uint(f);
  u += 0x7fffu + ((u >> 16) & 1u);   // round-to-nearest-even
  return (unsigned short)(u >> 16);
}

// -------- Kernel 1: fused prep. Blocks [0,TOKENS): LayerNorm fp32->bf16.
// Blocks [TOKENS, TOKENS+8192): W fp32->bf16 (32 elems/thread).
// Fusing lets the two memory-bound phases co-saturate HBM and saves a
// launch boundary. Branch is blockIdx-uniform (no divergent barriers).
__global__ __launch_bounds__(256) void prep_kernel(const float* __restrict__ x,
                                                   unsigned short* __restrict__ xn,
                                                   const float* __restrict__ W,
                                                   unsigned short* __restrict__ Wb) {
  if (blockIdx.x < TOKENS) {
    const int row = blockIdx.x;
    const float4* xr = reinterpret_cast<const float4*>(x + (size_t)row * DIN);
    float4 v[4];
    float sum = 0.f, ssq = 0.f;
#pragma unroll
    for (int i = 0; i < 4; ++i) {
      v[i] = xr[threadIdx.x + i * 256];
      sum += v[i].x + v[i].y + v[i].z + v[i].w;
      ssq += v[i].x * v[i].x + v[i].y * v[i].y + v[i].z * v[i].z + v[i].w * v[i].w;
    }
#pragma unroll
    for (int off = 32; off > 0; off >>= 1) {
      sum += __shfl_xor(sum, off, 64);
      ssq += __shfl_xor(ssq, off, 64);
    }
    __shared__ float red[8];
    const int wid = threadIdx.x >> 6;
    if ((threadIdx.x & 63) == 0) { red[wid] = sum; red[wid + 4] = ssq; }
    __syncthreads();
    sum = red[0] + red[1] + red[2] + red[3];
    ssq = red[4] + red[5] + red[6] + red[7];
    const float mean = sum * (1.f / DIN);
    const float var  = ssq * (1.f / DIN) - mean * mean;  // biased, as torch LN
    const float rs   = rsqrtf(var + 1e-5f);
    ushort4* xo = reinterpret_cast<ushort4*>(xn + (size_t)row * DIN);
#pragma unroll
    for (int i = 0; i < 4; ++i) {
      ushort4 o;
      o.x = f2bf((v[i].x - mean) * rs);
      o.y = f2bf((v[i].y - mean) * rs);
      o.z = f2bf((v[i].z - mean) * rs);
      o.w = f2bf((v[i].w - mean) * rs);
      xo[threadIdx.x + i * 256] = o;
    }
  } else {
    // cvt: 8192 blocks x 256 thr x 8 float4 = 64M floats
    const size_t base = (size_t)(blockIdx.x - TOKENS) * 2048 + threadIdx.x;
    const float4* Wf = reinterpret_cast<const float4*>(W);
    ushort4* Wo = reinterpret_cast<ushort4*>(Wb);
#pragma unroll
    for (int i = 0; i < 8; ++i) {
      float4 v = Wf[base + (size_t)i * 256];
      ushort4 o;
      o.x = f2bf(v.x); o.y = f2bf(v.y); o.z = f2bf(v.z); o.w = f2bf(v.w);
      Wo[base + (size_t)i * 256] = o;
    }
  }
}

// -------- Kernel 2: 256x256, 32x32x16 MFMA, 4-phase (R12 config — best
// measured: 1060-1072 us GEMM, MfmaUtil 52%).
// Structure: in-phase reads + mid-phase barrier + setprio; stages
// [A1 | A0'q02+B0'q01 | B0'q23+A0'q13 | B1'], vmcnt(4) at ph1/ph3 tops
// (both confirm 2-phase-old batches; non-blocking in steady state).
// Involution LDS swizzle (linear gload dest + inverse-swizzled global src
// + swizzled ds_read), 2x2 super-tile L2 grouping inside XCD chunks.
// Structural ceiling note: wave tile 128x64 -> acc=128 VGPR -> 256
// VGPR/wave -> 2 waves/SIMD (VGPR-forced); barrier-framed phases
// serialize LDS(~1400cy incl. inherent b128 overhead) + MFMA(1033cy);
// 7 schedule variants (R12-R17) all land within +-5% of this.
__global__ __launch_bounds__(512, 2) void gemm_sig(const unsigned short* __restrict__ A,
                                                   const unsigned short* __restrict__ B,
                                                   float* __restrict__ C) {
  __shared__ unsigned short Asl[2 * 256 * 64];  // 64 KB
  __shared__ unsigned short Bsl[2 * 256 * 64];  // 64 KB

  // XCD chunk (nwg=2048, cpx=256) then 2x2 super-tile grouping.
  const int bid = blockIdx.x;
  const int cpx = gridDim.x >> 3;              // 256
  const int swz = (bid & 7) * cpx + (bid >> 3);
  const int grp = swz >> 2;                    // 0..511 = 16 (bm) x 32 (bn)
  const int sub = swz & 3;
  const int bm = ((grp & 15) << 1) | (sub & 1);    // 0..31
  const int bn = ((grp >> 4) << 1) | (sub >> 1);   // 0..63

  const int tid  = threadIdx.x;
  const int wid  = tid >> 6;
  const int lane = tid & 63;
  const int wr = wid >> 2, wc = wid & 3;

  const unsigned short* gA = A + (size_t)bm * BM * DIN;
  const unsigned short* gB = B + (size_t)bn * BN * DIN;

  // Staging: 1 gload = 512 lanes x 16B = 8 KB = 64 rows (one quarter).
  // Lane l of wave wid writes LDS row wid*8+(l>>3), slot l&7 (linear dest);
  // fetches global slot (l&7)^(l>>3) (involution keyed on row&7).
  const int l8 = lane >> 3, l7 = lane & 7;
  const int csw = l7 ^ l8;
  const unsigned short* sA = gA + (size_t)(wid * 8 + l8) * DIN + csw * 8;
  const unsigned short* sB = gB + (size_t)(wid * 8 + l8) * DIN + csw * 8;
  const int dOfs = wid * 512;   // ushort units

#define STG_Aq(p, q, kt) __builtin_amdgcn_global_load_lds( \
    (const AS1 void*)(sA + (size_t)(q) * 64 * DIN + (size_t)(kt) * BKT), \
    (AS3 void*)(Asl + ((p) * 256 + (q) * 64) * 64 + dOfs), 16, 0, 0)
#define STG_Bq(p, q, kt) __builtin_amdgcn_global_load_lds( \
    (const AS1 void*)(sB + (size_t)(q) * 64 * DIN + (size_t)(kt) * BKT), \
    (AS3 void*)(Bsl + ((p) * 256 + (q) * 64) * 64 + dOfs), 16, 0, 0)

  // Read side (32x32 frags): row = base + (lane&31); logical k-slot for
  // kstep ks = 2*ks + (lane>>5); stored at slot ^ (row&7), row&7 = lane&7.
  const int l31 = lane & 31;
  const int l5  = lane >> 5;
  int aRow[4], bRow[2], kslt[4];
#pragma unroll
  for (int mb = 0; mb < 4; ++mb) aRow[mb] = (wr * 128 + mb * 32 + l31) * 64;
#pragma unroll
  for (int nb = 0; nb < 2; ++nb) bRow[nb] = (wc * 64 + nb * 32 + l31) * 64;
#pragma unroll
  for (int ks = 0; ks < 4; ++ks) kslt[ks] = ((2 * ks + l5) ^ l7) * 8;

  s16x8 a0[4], a1[4], b0[4], b1[4];
  f32x16 acc[4][2] = {};

#define RD_AP(p, mp) do { _Pragma("unroll") for (int ks = 0; ks < 4; ++ks) { \
    a0[ks] = *reinterpret_cast<const s16x8*>(Asl + (p) * 16384 + aRow[2 * (mp)] + kslt[ks]); \
    a1[ks] = *reinterpret_cast<const s16x8*>(Asl + (p) * 16384 + aRow[2 * (mp) + 1] + kslt[ks]); } } while (0)
#define RD_BALL(p) do { _Pragma("unroll") for (int ks = 0; ks < 4; ++ks) { \
    b0[ks] = *reinterpret_cast<const s16x8*>(Bsl + (p) * 16384 + bRow[0] + kslt[ks]); \
    b1[ks] = *reinterpret_cast<const s16x8*>(Bsl + (p) * 16384 + bRow[1] + kslt[ks]); } } while (0)
#define MMPH(mp) do { _Pragma("unroll") for (int ks = 0; ks < 4; ++ks) { \
    acc[2 * (mp)][0]     = __builtin_amdgcn_mfma_f32_32x32x16_bf16(a0[ks], b0[ks], acc[2 * (mp)][0], 0, 0, 0); \
    acc[2 * (mp)][1]     = __builtin_amdgcn_mfma_f32_32x32x16_bf16(a0[ks], b1[ks], acc[2 * (mp)][1], 0, 0, 0); \
    acc[2 * (mp) + 1][0] = __builtin_amdgcn_mfma_f32_32x32x16_bf16(a1[ks], b0[ks], acc[2 * (mp) + 1][0], 0, 0, 0); \
    acc[2 * (mp) + 1][1] = __builtin_amdgcn_mfma_f32_32x32x16_bf16(a1[ks], b1[ks], acc[2 * (mp) + 1][1], 0, 0, 0); } } while (0)

  // Prologue: t0 full (8) + B1(t1) (4). vmcnt(4) -> t0 confirmed.
  STG_Aq(0, 0, 0); STG_Aq(0, 1, 0); STG_Aq(0, 2, 0); STG_Aq(0, 3, 0);
  STG_Bq(0, 0, 0); STG_Bq(0, 1, 0); STG_Bq(0, 2, 0); STG_Bq(0, 3, 0);
  STG_Bq(1, 0, 1); STG_Bq(1, 1, 1); STG_Bq(1, 2, 1); STG_Bq(1, 3, 1);
  VMCNT(4); BAR();

  for (int j = 0; j < NJ - 1; ++j) {
    const int t1 = 2 * j + 1, t2 = 2 * j + 2, t3 = 2 * j + 3;
    // ph1: buf0 m-pair0 + B all (16 reads); stage A-buf1 q0-3 (t1)
    VMCNT(4);
    RD_AP(0, 0); RD_BALL(0);
    STG_Aq(1, 0, t1); STG_Aq(1, 1, t1); STG_Aq(1, 2, t1); STG_Aq(1, 3, t1);
    BAR(); PRIO1(); MMPH(0); PRIO0(); BAR();
    // ph2: buf0 m-pair1 (8 reads); stage A0'q0,q2 + B0'q0,q1 (t2)
    RD_AP(0, 1);
    STG_Aq(0, 0, t2); STG_Aq(0, 2, t2); STG_Bq(0, 0, t2); STG_Bq(0, 1, t2);
    BAR(); PRIO1(); MMPH(1); PRIO0(); BAR();
    // ph3: buf1 m-pair0 + B all; stage B0'q2,q3 + A0'q1,q3 (t2)
    VMCNT(4);
    RD_AP(1, 0); RD_BALL(1);
    STG_Bq(0, 2, t2); STG_Bq(0, 3, t2); STG_Aq(0, 1, t2); STG_Aq(0, 3, t2);
    BAR(); PRIO1(); MMPH(0); PRIO0(); BAR();
    // ph4: buf1 m-pair1; stage B1'q0-3 (t3)
    RD_AP(1, 1);
    STG_Bq(1, 0, t3); STG_Bq(1, 1, t3); STG_Bq(1, 2, t3); STG_Bq(1, 3, t3);
    BAR(); PRIO1(); MMPH(1); PRIO0(); BAR();
  }

  // Tail iter (t0 = NT-2, t1 = NT-1): only ph1's A-buf1 stage; drain at ph3.
  {
    const int t1 = NT - 1;
    VMCNT(4);
    RD_AP(0, 0); RD_BALL(0);
    STG_Aq(1, 0, t1); STG_Aq(1, 1, t1); STG_Aq(1, 2, t1); STG_Aq(1, 3, t1);
    BAR(); PRIO1(); MMPH(0); PRIO0(); BAR();
    RD_AP(0, 1);
    BAR(); PRIO1(); MMPH(1); PRIO0(); BAR();
    VMCNT(0);
    RD_AP(1, 0); RD_BALL(1);
    BAR(); PRIO1(); MMPH(0); PRIO0(); BAR();
    RD_AP(1, 1);
    BAR(); PRIO1(); MMPH(1); PRIO0(); BAR();
  }

#undef STG_Aq
#undef STG_Bq
#undef RD_AP
#undef RD_BALL
#undef MMPH

  // Epilogue: 32x32 C/D layout: col = lane&31,
  // row = (reg&3) + 8*(reg>>2) + 4*(lane>>5).
  const int crow0 = bm * BM + wr * 128 + 4 * l5;
  const int ccol0 = bn * BN + wc * 64 + l31;
#pragma unroll
  for (int mb = 0; mb < 4; ++mb)
#pragma unroll
    for (int nb = 0; nb < 2; ++nb)
#pragma unroll
      for (int reg = 0; reg < 16; ++reg) {
        const int r = crow0 + mb * 32 + (reg & 3) + 8 * (reg >> 2);
        const int c = ccol0 + nb * 32;
        const float v = acc[mb][nb][reg];
        C[(size_t)r * DOUT + c] = 1.f / (1.f + __expf(-v));
      }
}

extern "C" void kernel_launch(void* const* d_in, const int* in_sizes, int n_in,
                              void* d_out, int out_size, void* d_ws, size_t ws_size,
                              hipStream_t stream) {
  const float* x = (const float*)d_in[0];
  const float* W = (const float*)d_in[1];
  float* out = (float*)d_out;

  unsigned short* xn = (unsigned short*)d_ws;                    // 64 MiB
  unsigned short* Wb = xn + (size_t)TOKENS * DIN;                // 128 MiB

  prep_kernel<<<TOKENS + 8192, 256, 0, stream>>>(x, xn, W, Wb);
  gemm_sig<<<(TOKENS / BM) * (DOUT / BN), 512, 0, stream>>>(xn, Wb, out);
}